// Round 1
// baseline (928.959 us; speedup 1.0000x reference)
//
#include <hip/hip_runtime.h>

#define S_   2048
#define DM_  1024
#define NH_  16
#define HD_  64
#define NQ_  3072
#define KDIM 1024

typedef __attribute__((ext_vector_type(8))) short  shortx8;
typedef __attribute__((ext_vector_type(4))) float  floatx4;

#define AS1 __attribute__((address_space(1)))
#define AS3 __attribute__((address_space(3)))

__device__ __forceinline__ unsigned short f2bf(float f) {
  unsigned u = __float_as_uint(f);
  u += 0x7FFFu + ((u >> 16) & 1u);
  return (unsigned short)(u >> 16);
}

__device__ __forceinline__ void gld_lds16(const void* g, unsigned short* l) {
  __builtin_amdgcn_global_load_lds((const AS1 void*)g, (AS3 void*)l, 16, 0, 0);
}

// ---------------- dtype detection ----------------
// flags[0]: mask dtype  0=int32{0,1} 1=u8 bytes 2=bf16 3=f32 bits
// flags[1]: x/W/out are bf16 (1) or f32 (0)
__global__ __launch_bounds__(256) void detect_kernel(const unsigned* __restrict__ mask,
                                                     const unsigned* __restrict__ x,
                                                     int* __restrict__ flags)
{
  __shared__ int s[5];
  if (threadIdx.x == 0) { s[0]=1; s[1]=1; s[2]=1; s[3]=1; s[4]=0; }
  __syncthreads();
  bool o32=true, of32=true, o16=true, o8=true;
  for (int i = threadIdx.x; i < 16384; i += 256) {
    unsigned v = mask[i];
    o32 &= (v <= 1u);
    of32 &= (v == 0u) || (v == 0x3F800000u);
    unsigned lo = v & 0xFFFFu, hi = v >> 16;
    o16 &= ((lo==0u)||(lo==0x3F80u)) && ((hi==0u)||(hi==0x3F80u));
    o8  &= ((v & 0xFEFEFEFEu) == 0u);
  }
  int cnt = 0;
  for (int i = threadIdx.x; i < 4096; i += 256) {
    unsigned v = x[i];
    unsigned b1 = (v >> 8) & 0x7Fu;           // bf16 exp-ish byte vs f32 mantissa byte
    cnt += (b1 >= 0x32u && b1 <= 0x41u) ? 1 : 0;
  }
  if (!o32)  atomicAnd(&s[0], 0);
  if (!of32) atomicAnd(&s[1], 0);
  if (!o16)  atomicAnd(&s[2], 0);
  if (!o8)   atomicAnd(&s[3], 0);
  atomicAdd(&s[4], cnt);
  __syncthreads();
  if (threadIdx.x == 0) {
    int mf;
    if (s[0]) mf = 0; else if (s[1]) mf = 3; else if (s[2]) mf = 2; else mf = 1;
    flags[0] = mf;
    flags[1] = (s[4] > 2048) ? 1 : 0;
  }
}

// ---------------- QKV projection GEMM ----------------
// C[m][n] = sum_k X[m][k]*W[n][k]; M=4096 N=3072 K=1024; C stored bf16 in ws.
__global__ __launch_bounds__(256) void qkv_gemm(const void* __restrict__ Xv,
                                                const void* __restrict__ Wv,
                                                unsigned short* __restrict__ QKV,
                                                const int* __restrict__ flags)
{
  __shared__ unsigned short lA[128*64];
  __shared__ unsigned short lB[128*64];
  const int tid  = threadIdx.x;
  const int wid  = tid >> 6,  lane = tid & 63;
  const int quad = lane >> 4, l16  = lane & 15;
  const int bm = blockIdx.x, bn = blockIdx.y;
  const int wM = (wid >> 1) * 64, wN = (wid & 1) * 64;
  const int xbf = flags[1];

  floatx4 acc[4][4] = {};

  for (int kt = 0; kt < KDIM; kt += 64) {
    __syncthreads();
    if (xbf) {
      const unsigned short* X = (const unsigned short*)Xv;
      const unsigned short* W = (const unsigned short*)Wv;
      #pragma unroll
      for (int p = 0; p < 4; ++p) {
        int chunk = p*256 + tid;
        int r = chunk >> 3, c = chunk & 7;
        int csw = c ^ (r & 7);
        gld_lds16(X + (size_t)(bm*128 + r)*KDIM + kt + csw*8, lA + chunk*8);
      }
      #pragma unroll
      for (int p = 0; p < 4; ++p) {
        int chunk = p*256 + tid;
        int r = chunk >> 3, c = chunk & 7;
        int csw = c ^ (r & 7);
        gld_lds16(W + (size_t)(bn*128 + r)*KDIM + kt + csw*8, lB + chunk*8);
      }
    } else {
      const float* X = (const float*)Xv;
      const float* W = (const float*)Wv;
      #pragma unroll
      for (int p = 0; p < 8; ++p) {
        int c4 = p*256 + tid;
        int r = c4 >> 4, c = c4 & 15;
        int cg = c >> 1, half = c & 1;
        int csl = cg ^ (r & 7);
        float4 v = *(const float4*)(X + (size_t)(bm*128 + r)*KDIM + kt + c*4);
        unsigned short* d = lA + r*64 + csl*8 + half*4;
        d[0]=f2bf(v.x); d[1]=f2bf(v.y); d[2]=f2bf(v.z); d[3]=f2bf(v.w);
      }
      #pragma unroll
      for (int p = 0; p < 8; ++p) {
        int c4 = p*256 + tid;
        int r = c4 >> 4, c = c4 & 15;
        int cg = c >> 1, half = c & 1;
        int csl = cg ^ (r & 7);
        float4 v = *(const float4*)(W + (size_t)(bn*128 + r)*KDIM + kt + c*4);
        unsigned short* d = lB + r*64 + csl*8 + half*4;
        d[0]=f2bf(v.x); d[1]=f2bf(v.y); d[2]=f2bf(v.z); d[3]=f2bf(v.w);
      }
    }
    __syncthreads();

    #pragma unroll
    for (int ks = 0; ks < 2; ++ks) {
      shortx8 af[4], bfr[4];
      #pragma unroll
      for (int mi = 0; mi < 4; ++mi) {
        int r = wM + mi*16 + l16;
        int csw = (ks*4 + quad) ^ (r & 7);
        af[mi] = *(const shortx8*)(lA + r*64 + csw*8);
      }
      #pragma unroll
      for (int ni = 0; ni < 4; ++ni) {
        int r = wN + ni*16 + l16;
        int csw = (ks*4 + quad) ^ (r & 7);
        bfr[ni] = *(const shortx8*)(lB + r*64 + csw*8);
      }
      #pragma unroll
      for (int mi = 0; mi < 4; ++mi)
        #pragma unroll
        for (int ni = 0; ni < 4; ++ni)
          acc[mi][ni] = __builtin_amdgcn_mfma_f32_16x16x32_bf16(af[mi], bfr[ni], acc[mi][ni], 0, 0, 0);
    }
  }

  #pragma unroll
  for (int mi = 0; mi < 4; ++mi)
    #pragma unroll
    for (int ni = 0; ni < 4; ++ni)
      #pragma unroll
      for (int r = 0; r < 4; ++r) {
        int m = bm*128 + wM + mi*16 + quad*4 + r;   // C row = quad*4+reg (m89/m91)
        int n = bn*128 + wN + ni*16 + l16;          // C col = lane&15
        QKV[(size_t)m*NQ_ + n] = f2bf(acc[mi][ni][r]);
      }
}

// ---------------- fused masked flash attention ----------------
__global__ __launch_bounds__(256) void attn_kernel(const unsigned short* __restrict__ QKV,
                                                   const void* __restrict__ maskp,
                                                   const int* __restrict__ flags,
                                                   void* __restrict__ outv)
{
  __shared__ unsigned short lQ[64*64];
  __shared__ unsigned short lK[64*64];
  __shared__ unsigned short lVt[64*72];     // V^T, stride 72 (144 B: 16B-aligned, bank-friendly)
  __shared__ unsigned short lP[4][16*72];   // per-wave P round-trip

  const int tid  = threadIdx.x;
  const int wid  = tid >> 6,  lane = tid & 63;
  const int quad = lane >> 4, l16  = lane & 15;
  const int qb = blockIdx.x * 64;
  const int h  = blockIdx.y, b = blockIdx.z;
  const int mflag = flags[0];
  const int obf   = flags[1];

  // stage Q block (64 q x 64 d), swizzled
  #pragma unroll
  for (int p = 0; p < 2; ++p) {
    int chunk = p*256 + tid;
    int r = chunk >> 3, c = chunk & 7;
    int csw = c ^ (r & 7);
    gld_lds16(QKV + ((size_t)b*S_ + qb + r)*NQ_ + h*HD_ + csw*8, lQ + chunk*8);
  }
  __syncthreads();

  shortx8 qf[2];
  {
    int r = wid*16 + l16;
    #pragma unroll
    for (int ks = 0; ks < 2; ++ks) {
      int csw = (ks*4 + quad) ^ (r & 7);
      qf[ks] = *(const shortx8*)(lQ + r*64 + csw*8);
    }
  }

  floatx4 acc[4] = {};
  float mrun[4], lrun[4];
  #pragma unroll
  for (int r = 0; r < 4; ++r) { mrun[r] = -1e30f; lrun[r] = 0.f; }

  size_t mbase[4];
  #pragma unroll
  for (int r = 0; r < 4; ++r) {
    int q = qb + wid*16 + quad*4 + r;
    mbase[r] = (((size_t)b*S_ + q)*NH_ + h)*S_ + l16;
  }

  const size_t kvrow = (size_t)b*S_;

  for (int t0 = 0; t0 < S_; t0 += 64) {
    __syncthreads();
    // stage K chunk (64 t x 64 d), swizzled
    #pragma unroll
    for (int p = 0; p < 2; ++p) {
      int chunk = p*256 + tid;
      int r = chunk >> 3, c = chunk & 7;
      int csw = c ^ (r & 7);
      gld_lds16(QKV + (kvrow + t0 + r)*NQ_ + DM_ + h*HD_ + csw*8, lK + chunk*8);
    }
    // stage V^T (64 d x 64 t)
    #pragma unroll
    for (int p = 0; p < 2; ++p) {
      int chunk = p*256 + tid;
      int t = chunk >> 3, c = chunk & 7;
      uint4 w = *(const uint4*)(QKV + (kvrow + t0 + t)*NQ_ + 2*DM_ + h*HD_ + c*8);
      unsigned short e[8];
      __builtin_memcpy(e, &w, 16);
      #pragma unroll
      for (int j = 0; j < 8; ++j) lVt[(c*8 + j)*72 + t] = e[j];
    }
    __syncthreads();

    // scores: S = Q K^T
    floatx4 sc[4] = {};
    #pragma unroll
    for (int tile = 0; tile < 4; ++tile) {
      #pragma unroll
      for (int ks = 0; ks < 2; ++ks) {
        int r = tile*16 + l16;
        int csw = (ks*4 + quad) ^ (r & 7);
        shortx8 kf = *(const shortx8*)(lK + r*64 + csw*8);
        sc[tile] = __builtin_amdgcn_mfma_f32_16x16x32_bf16(qf[ks], kf, sc[tile], 0, 0, 0);
      }
    }

    float s[4][4];
    #pragma unroll
    for (int tile = 0; tile < 4; ++tile)
      #pragma unroll
      for (int r = 0; r < 4; ++r)
        s[tile][r] = sc[tile][r] * 0.125f;

    if (mflag == 0) {
      const int* mp = (const int*)maskp;
      #pragma unroll
      for (int tile = 0; tile < 4; ++tile)
        #pragma unroll
        for (int r = 0; r < 4; ++r)
          if (mp[mbase[r] + t0 + tile*16] == 0) s[tile][r] = -1e30f;
    } else if (mflag == 1) {
      const unsigned char* mp = (const unsigned char*)maskp;
      #pragma unroll
      for (int tile = 0; tile < 4; ++tile)
        #pragma unroll
        for (int r = 0; r < 4; ++r)
          if (mp[mbase[r] + t0 + tile*16] == 0) s[tile][r] = -1e30f;
    } else if (mflag == 2) {
      const unsigned short* mp = (const unsigned short*)maskp;
      #pragma unroll
      for (int tile = 0; tile < 4; ++tile)
        #pragma unroll
        for (int r = 0; r < 4; ++r)
          if (mp[mbase[r] + t0 + tile*16] == 0) s[tile][r] = -1e30f;
    } else {
      const unsigned* mp = (const unsigned*)maskp;
      #pragma unroll
      for (int tile = 0; tile < 4; ++tile)
        #pragma unroll
        for (int r = 0; r < 4; ++r)
          if (mp[mbase[r] + t0 + tile*16] == 0) s[tile][r] = -1e30f;
    }

    // online softmax (row stats across the 16 lanes of each quad)
    float pr[4][4];
    #pragma unroll
    for (int r = 0; r < 4; ++r) {
      float m0 = fmaxf(fmaxf(s[0][r], s[1][r]), fmaxf(s[2][r], s[3][r]));
      #pragma unroll
      for (int o = 1; o < 16; o <<= 1) m0 = fmaxf(m0, __shfl_xor(m0, o));
      float mnew = fmaxf(mrun[r], m0);
      float al = __expf(mrun[r] - mnew);
      mrun[r] = mnew;
      float ls = 0.f;
      #pragma unroll
      for (int tile = 0; tile < 4; ++tile) {
        float p_ = __expf(s[tile][r] - mnew);
        pr[tile][r] = p_; ls += p_;
      }
      #pragma unroll
      for (int o = 1; o < 16; o <<= 1) ls += __shfl_xor(ls, o);
      lrun[r] = lrun[r]*al + ls;
      #pragma unroll
      for (int d = 0; d < 4; ++d) acc[d][r] *= al;
    }

    // P: C-layout -> LDS -> A-layout (m120-verified round trip)
    unsigned short* lPw = lP[wid];
    #pragma unroll
    for (int tile = 0; tile < 4; ++tile)
      #pragma unroll
      for (int r = 0; r < 4; ++r)
        lPw[(quad*4 + r)*72 + tile*16 + l16] = f2bf(pr[tile][r]);

    #pragma unroll
    for (int ks = 0; ks < 2; ++ks) {
      shortx8 pa = *(const shortx8*)(lPw + l16*72 + ks*32 + quad*8);
      #pragma unroll
      for (int d = 0; d < 4; ++d) {
        shortx8 vb = *(const shortx8*)(lVt + (d*16 + l16)*72 + ks*32 + quad*8);
        acc[d] = __builtin_amdgcn_mfma_f32_16x16x32_bf16(pa, vb, acc[d], 0, 0, 0);
      }
    }
  }

  #pragma unroll
  for (int d = 0; d < 4; ++d)
    #pragma unroll
    for (int r = 0; r < 4; ++r) {
      int q = qb + wid*16 + quad*4 + r;
      size_t oi = ((size_t)b*S_ + q)*DM_ + h*HD_ + d*16 + l16;
      float v = acc[d][r] / lrun[r];
      if (obf) ((unsigned short*)outv)[oi] = f2bf(v);
      else     ((float*)outv)[oi]          = v;
    }
}

extern "C" void kernel_launch(void* const* d_in, const int* in_sizes, int n_in,
                              void* d_out, int out_size, void* d_ws, size_t ws_size,
                              hipStream_t stream) {
  (void)in_sizes; (void)n_in; (void)out_size; (void)ws_size;
  const void* X    = d_in[0];
  const void* W    = d_in[1];
  const void* mask = d_in[2];
  int* flags = (int*)d_ws;
  unsigned short* QKV = (unsigned short*)((char*)d_ws + 256);  // 4096x3072 bf16 = 25.2 MB

  detect_kernel<<<1, 256, 0, stream>>>((const unsigned*)mask, (const unsigned*)X, flags);
  qkv_gemm<<<dim3(32, 24), 256, 0, stream>>>(X, W, QKV, flags);
  attn_kernel<<<dim3(32, 16, 2), 256, 0, stream>>>(QKV, mask, flags, d_out);
}

// Round 2
// 882.240 us; speedup vs baseline: 1.0530x; 1.0530x over previous
//
#include <hip/hip_runtime.h>

#define S_   2048
#define DM_  1024
#define NH_  16
#define HD_  64
#define KDIM 1024

typedef __attribute__((ext_vector_type(8))) short  shortx8;
typedef __attribute__((ext_vector_type(4))) float  floatx4;

#define AS1 __attribute__((address_space(1)))
#define AS3 __attribute__((address_space(3)))

__device__ __forceinline__ unsigned short f2bf(float f) {
  unsigned u = __float_as_uint(f);
  u += 0x7FFFu + ((u >> 16) & 1u);
  return (unsigned short)(u >> 16);
}

__device__ __forceinline__ void gld_lds16(const void* g, unsigned short* l) {
  __builtin_amdgcn_global_load_lds((const AS1 void*)g, (AS3 void*)l, 16, 0, 0);
}

// ---------------- dtype detection ----------------
// flags[0]: mask dtype  0=int32{0,1} 1=u8 bytes 2=bf16 3=f32 bits
// flags[1]: x/W/out are bf16 (1) or f32 (0)
__global__ __launch_bounds__(256) void detect_kernel(const unsigned* __restrict__ mask,
                                                     const unsigned* __restrict__ x,
                                                     int* __restrict__ flags)
{
  __shared__ int s[5];
  if (threadIdx.x == 0) { s[0]=1; s[1]=1; s[2]=1; s[3]=1; s[4]=0; }
  __syncthreads();
  bool o32=true, of32=true, o16=true, o8=true;
  for (int i = threadIdx.x; i < 16384; i += 256) {
    unsigned v = mask[i];
    o32 &= (v <= 1u);
    of32 &= (v == 0u) || (v == 0x3F800000u);
    unsigned lo = v & 0xFFFFu, hi = v >> 16;
    o16 &= ((lo==0u)||(lo==0x3F80u)) && ((hi==0u)||(hi==0x3F80u));
    o8  &= ((v & 0xFEFEFEFEu) == 0u);
  }
  int cnt = 0;
  for (int i = threadIdx.x; i < 4096; i += 256) {
    unsigned v = x[i];
    unsigned b1 = (v >> 8) & 0x7Fu;
    cnt += (b1 >= 0x32u && b1 <= 0x41u) ? 1 : 0;
  }
  if (!o32)  atomicAnd(&s[0], 0);
  if (!of32) atomicAnd(&s[1], 0);
  if (!o16)  atomicAnd(&s[2], 0);
  if (!o8)   atomicAnd(&s[3], 0);
  atomicAdd(&s[4], cnt);
  __syncthreads();
  if (threadIdx.x == 0) {
    int mf;
    if (s[0]) mf = 0; else if (s[1]) mf = 3; else if (s[2]) mf = 2; else mf = 1;
    flags[0] = mf;
    flags[1] = (s[4] > 2048) ? 1 : 0;
  }
}

// ---------------- QKV projection GEMM (m97 structure, no swizzle) ----------------
// C[m][n] = sum_k X[m][k]*W[n][k]; writes Qg/Kg [b][h][s][d] (Q pre-scaled) and Vt [b][h][d][s].
__global__ __launch_bounds__(256) void qkv_gemm(const void* __restrict__ Xv,
                                                const void* __restrict__ Wv,
                                                unsigned short* __restrict__ Qg,
                                                unsigned short* __restrict__ Kg,
                                                unsigned short* __restrict__ Vt,
                                                const int* __restrict__ flags)
{
  __shared__ unsigned short lA[128*64];
  __shared__ unsigned short lB[128*64];
  const int tid  = threadIdx.x;
  const int wid  = tid >> 6,  lane = tid & 63;
  const int quad = lane >> 4, l16  = lane & 15;
  const int bm = blockIdx.x, bn = blockIdx.y;
  const int wM = (wid >> 1) * 64, wN = (wid & 1) * 64;
  const int xbf = flags[1];

  floatx4 acc[4][4] = {};

  for (int kt = 0; kt < KDIM; kt += 64) {
    __syncthreads();
    if (xbf) {
      const unsigned short* X = (const unsigned short*)Xv;
      const unsigned short* W = (const unsigned short*)Wv;
      #pragma unroll
      for (int p = 0; p < 4; ++p) {
        int chunk = p*256 + tid;
        int r = chunk >> 3, c = chunk & 7;
        gld_lds16(X + (size_t)(bm*128 + r)*KDIM + kt + c*8, lA + chunk*8);
      }
      #pragma unroll
      for (int p = 0; p < 4; ++p) {
        int chunk = p*256 + tid;
        int r = chunk >> 3, c = chunk & 7;
        gld_lds16(W + (size_t)(bn*128 + r)*KDIM + kt + c*8, lB + chunk*8);
      }
    } else {
      const float* X = (const float*)Xv;
      const float* W = (const float*)Wv;
      #pragma unroll
      for (int p = 0; p < 8; ++p) {
        int c4 = p*256 + tid;
        int r = c4 >> 4, c = c4 & 15;
        float4 v = *(const float4*)(X + (size_t)(bm*128 + r)*KDIM + kt + c*4);
        unsigned short* d = lA + r*64 + c*4;
        d[0]=f2bf(v.x); d[1]=f2bf(v.y); d[2]=f2bf(v.z); d[3]=f2bf(v.w);
      }
      #pragma unroll
      for (int p = 0; p < 8; ++p) {
        int c4 = p*256 + tid;
        int r = c4 >> 4, c = c4 & 15;
        float4 v = *(const float4*)(W + (size_t)(bn*128 + r)*KDIM + kt + c*4);
        unsigned short* d = lB + r*64 + c*4;
        d[0]=f2bf(v.x); d[1]=f2bf(v.y); d[2]=f2bf(v.z); d[3]=f2bf(v.w);
      }
    }
    __syncthreads();

    #pragma unroll
    for (int ks = 0; ks < 2; ++ks) {
      shortx8 af[4], bfr[4];
      #pragma unroll
      for (int mi = 0; mi < 4; ++mi)
        af[mi] = *(const shortx8*)(lA + (wM + mi*16 + l16)*64 + ks*32 + quad*8);
      #pragma unroll
      for (int ni = 0; ni < 4; ++ni)
        bfr[ni] = *(const shortx8*)(lB + (wN + ni*16 + l16)*64 + ks*32 + quad*8);
      #pragma unroll
      for (int mi = 0; mi < 4; ++mi)
        #pragma unroll
        for (int ni = 0; ni < 4; ++ni)
          acc[mi][ni] = __builtin_amdgcn_mfma_f32_16x16x32_bf16(af[mi], bfr[ni], acc[mi][ni], 0, 0, 0);
    }
  }

  // epilogue: per-region layouts. n<1024: Q (scaled), <2048: K, else V transposed.
  if (bn < 8) {
    #pragma unroll
    for (int mi = 0; mi < 4; ++mi)
      #pragma unroll
      for (int ni = 0; ni < 4; ++ni)
        #pragma unroll
        for (int r = 0; r < 4; ++r) {
          int m = bm*128 + wM + mi*16 + quad*4 + r;
          int n = bn*128 + wN + ni*16 + l16;
          int b = m >> 11, q = m & 2047, h = n >> 6, d = n & 63;
          Qg[(((size_t)(b*NH_ + h))*S_ + q)*HD_ + d] = f2bf(acc[mi][ni][r] * 0.125f);
        }
  } else if (bn < 16) {
    #pragma unroll
    for (int mi = 0; mi < 4; ++mi)
      #pragma unroll
      for (int ni = 0; ni < 4; ++ni)
        #pragma unroll
        for (int r = 0; r < 4; ++r) {
          int m = bm*128 + wM + mi*16 + quad*4 + r;
          int n = bn*128 + wN + ni*16 + l16 - 1024;
          int b = m >> 11, t = m & 2047, h = n >> 6, d = n & 63;
          Kg[(((size_t)(b*NH_ + h))*S_ + t)*HD_ + d] = f2bf(acc[mi][ni][r]);
        }
  } else {
    #pragma unroll
    for (int mi = 0; mi < 4; ++mi)
      #pragma unroll
      for (int ni = 0; ni < 4; ++ni) {
        int m0 = bm*128 + wM + mi*16 + quad*4;
        int n  = bn*128 + wN + ni*16 + l16 - 2048;
        int b = m0 >> 11, t = m0 & 2047, h = n >> 6, d = n & 63;
        ushort4 u;
        u.x = f2bf(acc[mi][ni][0]); u.y = f2bf(acc[mi][ni][1]);
        u.z = f2bf(acc[mi][ni][2]); u.w = f2bf(acc[mi][ni][3]);
        *(ushort4*)(Vt + (((size_t)(b*NH_ + h))*HD_ + d)*S_ + t) = u;
      }
  }
}

// ---------------- fused masked flash attention (max-free) ----------------
__global__ __launch_bounds__(256) void attn_kernel(const unsigned short* __restrict__ Qg,
                                                   const unsigned short* __restrict__ Kg,
                                                   const unsigned short* __restrict__ Vt,
                                                   const void* __restrict__ maskp,
                                                   const int* __restrict__ flags,
                                                   void* __restrict__ outv)
{
  __shared__ unsigned short lQ[64*64];
  __shared__ unsigned short lK[64*64];
  __shared__ unsigned short lVt[64*64];     // natural [d][t], staged linearly
  __shared__ unsigned short lP[4][16*72];   // per-wave P round-trip (stride 72)

  const int tid  = threadIdx.x;
  const int wid  = tid >> 6,  lane = tid & 63;
  const int quad = lane >> 4, l16  = lane & 15;
  const int qb = blockIdx.x * 64;
  const int h  = blockIdx.y, b = blockIdx.z;
  const int bh = b*NH_ + h;
  const int mflag = flags[0];
  const int obf   = flags[1];

  // stage Q block (contiguous 8 KB)
  #pragma unroll
  for (int p = 0; p < 2; ++p) {
    int chunk = p*256 + tid;
    gld_lds16(Qg + ((size_t)bh*S_ + qb)*HD_ + chunk*8, lQ + chunk*8);
  }
  __syncthreads();

  shortx8 qf[2];
  #pragma unroll
  for (int ks = 0; ks < 2; ++ks)
    qf[ks] = *(const shortx8*)(lQ + (wid*16 + l16)*64 + ks*32 + quad*8);

  floatx4 acc[4] = {};
  float lsum[4] = {0.f, 0.f, 0.f, 0.f};

  size_t mbase[4];
  #pragma unroll
  for (int r = 0; r < 4; ++r) {
    int q = qb + wid*16 + quad*4 + r;
    mbase[r] = (((size_t)b*S_ + q)*NH_ + h)*S_ + l16;
  }

  for (int t0 = 0; t0 < S_; t0 += 64) {
    __syncthreads();
    #pragma unroll
    for (int p = 0; p < 2; ++p) {
      int chunk = p*256 + tid;
      gld_lds16(Kg + ((size_t)bh*S_ + t0)*HD_ + chunk*8, lK + chunk*8);
    }
    #pragma unroll
    for (int p = 0; p < 2; ++p) {
      int chunk = p*256 + tid;
      int r = chunk >> 3, c = chunk & 7;
      gld_lds16(Vt + ((size_t)bh*HD_ + r)*S_ + t0 + c*8, lVt + chunk*8);
    }

    // mask loads overlap staging (drained by the barrier)
    unsigned mnz[4][4];
    if (mflag == 0) {
      const unsigned* mp = (const unsigned*)maskp;
      #pragma unroll
      for (int tile = 0; tile < 4; ++tile)
        #pragma unroll
        for (int r = 0; r < 4; ++r) mnz[tile][r] = mp[mbase[r] + t0 + tile*16];
    } else if (mflag == 1) {
      const unsigned char* mp = (const unsigned char*)maskp;
      #pragma unroll
      for (int tile = 0; tile < 4; ++tile)
        #pragma unroll
        for (int r = 0; r < 4; ++r) mnz[tile][r] = mp[mbase[r] + t0 + tile*16];
    } else if (mflag == 2) {
      const unsigned short* mp = (const unsigned short*)maskp;
      #pragma unroll
      for (int tile = 0; tile < 4; ++tile)
        #pragma unroll
        for (int r = 0; r < 4; ++r) mnz[tile][r] = mp[mbase[r] + t0 + tile*16];
    } else {
      const unsigned* mp = (const unsigned*)maskp;
      #pragma unroll
      for (int tile = 0; tile < 4; ++tile)
        #pragma unroll
        for (int r = 0; r < 4; ++r) mnz[tile][r] = mp[mbase[r] + t0 + tile*16];
    }
    __syncthreads();

    // S = Q K^T (Q pre-scaled by 1/8)
    floatx4 sc[4] = {};
    #pragma unroll
    for (int tile = 0; tile < 4; ++tile)
      #pragma unroll
      for (int ks = 0; ks < 2; ++ks) {
        shortx8 kf = *(const shortx8*)(lK + (tile*16 + l16)*64 + ks*32 + quad*8);
        sc[tile] = __builtin_amdgcn_mfma_f32_16x16x32_bf16(qf[ks], kf, sc[tile], 0, 0, 0);
      }

    // max-free softmax: p = mask ? exp(s) : 0 ; defer sum reduction
    float pv[4][4];
    #pragma unroll
    for (int tile = 0; tile < 4; ++tile)
      #pragma unroll
      for (int r = 0; r < 4; ++r) {
        float e = __expf(sc[tile][r]);
        pv[tile][r] = mnz[tile][r] ? e : 0.f;
        lsum[r] += pv[tile][r];
      }

    unsigned short* lPw = lP[wid];
    #pragma unroll
    for (int tile = 0; tile < 4; ++tile)
      #pragma unroll
      for (int r = 0; r < 4; ++r)
        lPw[(quad*4 + r)*72 + tile*16 + l16] = f2bf(pv[tile][r]);

    #pragma unroll
    for (int ks = 0; ks < 2; ++ks) {
      shortx8 pa = *(const shortx8*)(lPw + l16*72 + ks*32 + quad*8);
      #pragma unroll
      for (int d = 0; d < 4; ++d) {
        shortx8 vb = *(const shortx8*)(lVt + (d*16 + l16)*64 + ks*32 + quad*8);
        acc[d] = __builtin_amdgcn_mfma_f32_16x16x32_bf16(pa, vb, acc[d], 0, 0, 0);
      }
    }
  }

  // one deferred reduction of l across the 16 lanes of each quad
  float rinv[4];
  #pragma unroll
  for (int r = 0; r < 4; ++r) {
    float l = lsum[r];
    #pragma unroll
    for (int o = 1; o < 16; o <<= 1) l += __shfl_xor(l, o);
    rinv[r] = 1.f / l;
  }

  #pragma unroll
  for (int d = 0; d < 4; ++d)
    #pragma unroll
    for (int r = 0; r < 4; ++r) {
      int q = qb + wid*16 + quad*4 + r;
      size_t oi = ((size_t)b*S_ + q)*DM_ + h*HD_ + d*16 + l16;
      float v = acc[d][r] * rinv[r];
      if (obf) ((unsigned short*)outv)[oi] = f2bf(v);
      else     ((float*)outv)[oi]          = v;
    }
}

extern "C" void kernel_launch(void* const* d_in, const int* in_sizes, int n_in,
                              void* d_out, int out_size, void* d_ws, size_t ws_size,
                              hipStream_t stream) {
  (void)in_sizes; (void)n_in; (void)out_size; (void)ws_size;
  const void* X    = d_in[0];
  const void* W    = d_in[1];
  const void* mask = d_in[2];
  int* flags = (int*)d_ws;
  const size_t SEG = (size_t)2*NH_*S_*HD_*2;  // 8.39 MB per tensor
  unsigned short* Qg = (unsigned short*)((char*)d_ws + 256);
  unsigned short* Kg = (unsigned short*)((char*)d_ws + 256 + SEG);
  unsigned short* Vt = (unsigned short*)((char*)d_ws + 256 + 2*SEG);

  detect_kernel<<<1, 256, 0, stream>>>((const unsigned*)mask, (const unsigned*)X, flags);
  qkv_gemm<<<dim3(32, 24), 256, 0, stream>>>(X, W, Qg, Kg, Vt, flags);
  attn_kernel<<<dim3(32, 16, 2), 256, 0, stream>>>(Qg, Kg, Vt, mask, flags, d_out);
}